// Round 10
// baseline (804.478 us; speedup 1.0000x reference)
//
#include <hip/hip_runtime.h>

// B=16, LQ=LP=2048, H=1024
//   q_lin = relu(q @ W^T + b); p_lin = relu(p @ W^T + b)
//   scores = p_lin @ q_lin^T ; att = softmax(scores); out = att @ q_lin
// GEMMs: 256x256 tile, BK=64, 8 waves, fp16 MFMA 16x16x32.
// Round-10: B-operand loaded global->registers (fragment layout direct),
// A-only in LDS (64KB, double-buffered). LDS traffic/K-tile 240->160KB —
// r6-r9 showed the LDS data pipe (not barriers) was the 38%-MfmaUtil wall.
// One barrier + one vmcnt(8) per K-tile; sched_barrier pins A-GLPs ahead of
// B-loads so vmcnt(8) retires exactly the 4 A stage writes.

#define LQN 2048
#define LPN 2048
#define HD  1024
#define NBATCH 16

typedef _Float16 half8 __attribute__((ext_vector_type(8)));
typedef _Float16 half4_t __attribute__((ext_vector_type(4)));
typedef float f32x4 __attribute__((ext_vector_type(4)));

#define GLP(src, dst) __builtin_amdgcn_global_load_lds(                          \
    (const __attribute__((address_space(1))) void*)(src),                        \
    (__attribute__((address_space(3))) void*)(dst), 16, 0, 0)

// ---------------------------------------------------------------- convert f32->f16
__global__ __launch_bounds__(256) void cvt_f32_f16(const float* __restrict__ in,
                                                   _Float16* __restrict__ out,
                                                   long n4) {
  long i0 = (long)blockIdx.x * blockDim.x + threadIdx.x;
  long stride = (long)gridDim.x * blockDim.x;
  for (long i = i0; i < n4; i += stride) {
    float4 v = ((const float4*)in)[i];
    half4_t h = {(_Float16)v.x, (_Float16)v.y, (_Float16)v.z, (_Float16)v.w};
    ((half4_t*)out)[i] = h;
  }
}

// ---------------------------------------------------------------- tiled transpose
__global__ __launch_bounds__(256) void transpose_k(const _Float16* __restrict__ in,
                                                   _Float16* __restrict__ out) {
  __shared__ _Float16 t[64][72];
  const int bz = blockIdx.z;
  const int q0 = blockIdx.x * 64;
  const int d0 = blockIdx.y * 64;
  const int tt = threadIdx.x;
  const int ql = tt & 63, dg = tt >> 6;
  const _Float16* src = in + ((size_t)bz * LQN + q0 + ql) * HD + d0 + dg * 16;
  half8 v0 = *(const half8*)(src);
  half8 v1 = *(const half8*)(src + 8);
  int g0 = (dg * 2) ^ (ql & 7);
  int g1 = (dg * 2 + 1) ^ (ql & 7);
  *(half8*)&t[ql][g0 * 8] = v0;
  *(half8*)&t[ql][g1 * 8] = v1;
  __syncthreads();
  const int dl = tt & 63, qg = tt >> 6;
  half8 o0, o1;
#pragma unroll
  for (int j = 0; j < 8; ++j) {
    int qq = qg * 16 + j;
    o0[j] = t[qq][(((dl >> 3) ^ (qq & 7)) << 3) + (dl & 7)];
  }
#pragma unroll
  for (int j = 0; j < 8; ++j) {
    int qq = qg * 16 + 8 + j;
    o1[j] = t[qq][(((dl >> 3) ^ (qq & 7)) << 3) + (dl & 7)];
  }
  _Float16* dst = out + ((size_t)bz * HD + d0 + dl) * LQN + q0 + qg * 16;
  *(half8*)dst = o0;
  *(half8*)(dst + 8) = o1;
}

// ---------------------------------------------------------------- GEMM, B-in-regs
// EPI 0: f32 C (+z*sCz).  EPI 1: fp16 C = relu(acc+bias).
// EPI 2: fp16 P_t = exp(s - m_t) per 256-col tile + side (m_t, sum_t).

#define STAGEA_FULL(t, buf) do {                                                  \
  GLP(gA + (size_t)(t)*64,                      smW + (buf)*32768 + wid*1024);    \
  GLP(gA + (size_t)64*lda  + (size_t)(t)*64,    smW + (buf)*32768 +  8192 + wid*1024); \
  GLP(gA + (size_t)128*lda + (size_t)(t)*64,    smW + (buf)*32768 + 16384 + wid*1024); \
  GLP(gA + (size_t)192*lda + (size_t)(t)*64,    smW + (buf)*32768 + 24576 + wid*1024); \
} while (0)

#define LOADB_G(dst, t)                                                           \
  _Pragma("unroll")                                                               \
  for (int nb = 0; nb < 4; ++nb) {                                                \
    dst[nb][0] = *(const half8*)(gBr + (size_t)(nb) * 64 * ldb + (size_t)(t)*64); \
    dst[nb][1] = *(const half8*)(gBr + (size_t)(nb) * 64 * ldb + (size_t)(t)*64 + 32); \
  }

#define LOADA_H(qm, buf)                                                          \
  _Pragma("unroll")                                                               \
  for (int mi = 0; mi < 4; ++mi) {                                                \
    aA[mi][0] = *(const half8*)(smA + (buf)*32768 + a0 + ((qm)*4+mi)*4096);       \
    aA[mi][1] = *(const half8*)(smA + (buf)*32768 + a1 + ((qm)*4+mi)*4096);       \
  }

#define DO_HALF(qm, bs)                                                           \
  _Pragma("unroll")                                                               \
  for (int mi = 0; mi < 4; ++mi) {                                                \
    _Pragma("unroll")                                                             \
    for (int nb = 0; nb < 4; ++nb) {                                              \
      acc[(qm)*4+mi][nb] = __builtin_amdgcn_mfma_f32_16x16x32_f16(                \
          aA[mi][0], bs[nb][0], acc[(qm)*4+mi][nb], 0, 0, 0);                     \
      acc[(qm)*4+mi][nb] = __builtin_amdgcn_mfma_f32_16x16x32_f16(                \
          aA[mi][1], bs[nb][1], acc[(qm)*4+mi][nb], 0, 0, 0);                     \
    }                                                                             \
  }

#define TILE_SYNC                                       \
  __builtin_amdgcn_s_setprio(0);                        \
  __builtin_amdgcn_sched_barrier(0);                    \
  asm volatile("s_waitcnt vmcnt(8)" ::: "memory");      \
  __builtin_amdgcn_s_barrier();                         \
  __builtin_amdgcn_sched_barrier(0);

template <int EPI>
__global__ __launch_bounds__(512, 2) void gemm8p(
    const _Float16* __restrict__ A, const _Float16* __restrict__ B,
    const float* __restrict__ bias, void* __restrict__ Cv,
    float2* __restrict__ side, int K, int lda, int ldb, int ldc,
    long sAz, long sBz, long sCz) {
  extern __shared__ __align__(16) char smem[];
  const char* smA = smem;   // A tiles: 2 x 32KB (all of LDS)
  char* smW = smem;

  const int tid = threadIdx.x;
  const int lane = tid & 63, wid = tid >> 6;
  const int l16 = lane & 15, lhi = lane >> 4;
  const int wr = wid >> 2, wcn = wid & 3;

  // N-fast + XCD-chunked mapping
  const int nx = gridDim.x;
  const int d = blockIdx.y * nx + blockIdx.x;
  const int cpx = (nx * gridDim.y) >> 3;
  const int t_ = (d & 7) * cpx + (d >> 3);
  const int xsh = 31 - __builtin_clz(nx);
  const int bn0 = (t_ & (nx - 1)) << 8;
  const int bm0 = (t_ >> xsh) << 8;

  // A-LDS swizzle: flip 16B-slot bits 4-6 by row bits 0-2
  const int mask = (l16 & 7) << 4;
  const int a0 = (wr * 2048 + l16 * 128 + lhi * 16) ^ mask;
  const int a1 = a0 ^ 64;

  const int srow = tid >> 3;
  const int scol = (((tid & 7) ^ ((tid >> 3) & 7)) << 3);

  const _Float16* gA = A + (size_t)blockIdx.z * sAz + (size_t)(bm0 + srow) * lda + scol;
  // B fragment source: lane (l16,lhi) reads B[bn0 + nb*64 + wcn*16 + l16][t*64 + ks*32 + lhi*8]
  const _Float16* gBr = B + (size_t)blockIdx.z * sBz +
                        (size_t)(bn0 + wcn * 16 + l16) * ldb + lhi * 8;

  const int NT = K >> 6, NI = K >> 7;

  f32x4 acc[8][4] = {};
  half8 aA[4][2], bsE[4][2], bsO[4][2];

  // prologue: A(0)->buf0, B(0)->bsE; retire A(0) (vmcnt: 12 outstanding -> 8)
  STAGEA_FULL(0, 0);
  __builtin_amdgcn_sched_barrier(0);
  LOADB_G(bsE, 0)
  __builtin_amdgcn_sched_barrier(0);
  asm volatile("s_waitcnt vmcnt(8)" ::: "memory");
  __builtin_amdgcn_s_barrier();
  __builtin_amdgcn_sched_barrier(0);

  for (int i = 0; i < NI; ++i) {
    const int tEn = 2 * i + 1;
    int tOn = 2 * i + 2; if (tOn > NT - 1) tOn = NT - 1;
    // ---- even tile 2i [buf0, bsE]; prefetch tile 2i+1 -> buf1/bsO
    STAGEA_FULL(tEn, 1);
    __builtin_amdgcn_sched_barrier(0);
    LOADB_G(bsO, tEn)
    LOADA_H(0, 0);
    __builtin_amdgcn_s_setprio(1);
    DO_HALF(0, bsE)
    LOADA_H(1, 0);
    DO_HALF(1, bsE)
    TILE_SYNC
    // ---- odd tile 2i+1 [buf1, bsO]; prefetch tile 2i+2 -> buf0/bsE
    STAGEA_FULL(tOn, 0);
    __builtin_amdgcn_sched_barrier(0);
    LOADB_G(bsE, tOn)
    LOADA_H(0, 1);
    __builtin_amdgcn_s_setprio(1);
    DO_HALF(0, bsO)
    LOADA_H(1, 1);
    DO_HALF(1, bsO)
    TILE_SYNC
  }

  // drain all staging before LDS reuse / exit
  __builtin_amdgcn_sched_barrier(0);
  asm volatile("s_waitcnt vmcnt(0)" ::: "memory");
  __builtin_amdgcn_s_barrier();

  if constexpr (EPI == 0) {
    float* Cb = (float*)Cv + (size_t)blockIdx.z * sCz;
#pragma unroll
    for (int m = 0; m < 8; ++m) {
      int row0 = bm0 + m * 32 + wr * 16 + lhi * 4;
#pragma unroll
      for (int n = 0; n < 4; ++n) {
        int col = bn0 + n * 64 + wcn * 16 + l16;
#pragma unroll
        for (int v = 0; v < 4; ++v)
          Cb[(size_t)(row0 + v) * ldc + col] = acc[m][n][v];
      }
    }
  } else if constexpr (EPI == 1) {
    _Float16* Cb = (_Float16*)Cv;
#pragma unroll
    for (int n = 0; n < 4; ++n) {
      int col = bn0 + n * 64 + wcn * 16 + l16;
      float bv = bias[col];
#pragma unroll
      for (int m = 0; m < 8; ++m) {
        int row0 = bm0 + m * 32 + wr * 16 + lhi * 4;
        Cb[(size_t)(row0 + 0) * ldc + col] = (_Float16)fmaxf(acc[m][n][0] + bv, 0.f);
        Cb[(size_t)(row0 + 1) * ldc + col] = (_Float16)fmaxf(acc[m][n][1] + bv, 0.f);
        Cb[(size_t)(row0 + 2) * ldc + col] = (_Float16)fmaxf(acc[m][n][2] + bv, 0.f);
        Cb[(size_t)(row0 + 3) * ldc + col] = (_Float16)fmaxf(acc[m][n][3] + bv, 0.f);
      }
    }
  } else {
    // EPI == 2: partial softmax over this block's 256 cols (LDS reused, drained above)
    float* redm = (float*)smW;            // [256][4]
    float* reds = (float*)(smW + 4096);   // [256][4]
    float tm[8][4];
#pragma unroll
    for (int m = 0; m < 8; ++m)
#pragma unroll
      for (int v = 0; v < 4; ++v)
        tm[m][v] = fmaxf(fmaxf(acc[m][0][v], acc[m][1][v]),
                         fmaxf(acc[m][2][v], acc[m][3][v]));
#pragma unroll
    for (int o = 1; o < 16; o <<= 1)
#pragma unroll
      for (int m = 0; m < 8; ++m)
#pragma unroll
        for (int v = 0; v < 4; ++v)
          tm[m][v] = fmaxf(tm[m][v], __shfl_xor(tm[m][v], o));
    if (l16 == 0) {
#pragma unroll
      for (int m = 0; m < 8; ++m)
#pragma unroll
        for (int v = 0; v < 4; ++v)
          redm[(m * 32 + wr * 16 + lhi * 4 + v) * 4 + wcn] = tm[m][v];
    }
    __syncthreads();
    float rm[8][4], rs[8][4];
#pragma unroll
    for (int m = 0; m < 8; ++m)
#pragma unroll
      for (int v = 0; v < 4; ++v) {
        float4 q4 = ((const float4*)redm)[m * 32 + wr * 16 + lhi * 4 + v];
        rm[m][v] = fmaxf(fmaxf(q4.x, q4.y), fmaxf(q4.z, q4.w));
      }
#pragma unroll
    for (int m = 0; m < 8; ++m)
#pragma unroll
      for (int v = 0; v < 4; ++v) {
        float s = 0.f;
#pragma unroll
        for (int n = 0; n < 4; ++n) {
          float e = __expf(acc[m][n][v] - rm[m][v]);
          acc[m][n][v] = e;
          s += e;
        }
        tm[m][v] = s;
      }
#pragma unroll
    for (int o = 1; o < 16; o <<= 1)
#pragma unroll
      for (int m = 0; m < 8; ++m)
#pragma unroll
        for (int v = 0; v < 4; ++v)
          tm[m][v] += __shfl_xor(tm[m][v], o);
    __syncthreads();
    if (l16 == 0) {
#pragma unroll
      for (int m = 0; m < 8; ++m)
#pragma unroll
        for (int v = 0; v < 4; ++v)
          reds[(m * 32 + wr * 16 + lhi * 4 + v) * 4 + wcn] = tm[m][v];
    }
    __syncthreads();
#pragma unroll
    for (int m = 0; m < 8; ++m)
#pragma unroll
      for (int v = 0; v < 4; ++v) {
        float4 q4 = ((const float4*)reds)[m * 32 + wr * 16 + lhi * 4 + v];
        rs[m][v] = (q4.x + q4.y) + (q4.z + q4.w);
      }
    _Float16* Cb = (_Float16*)Cv + (size_t)blockIdx.z * sCz;
#pragma unroll
    for (int n = 0; n < 4; ++n) {
      int col = bn0 + n * 64 + wcn * 16 + l16;
#pragma unroll
      for (int m = 0; m < 8; ++m) {
        int row0 = bm0 + m * 32 + wr * 16 + lhi * 4;
        Cb[(size_t)(row0 + 0) * ldc + col] = (_Float16)acc[m][n][0];
        Cb[(size_t)(row0 + 1) * ldc + col] = (_Float16)acc[m][n][1];
        Cb[(size_t)(row0 + 2) * ldc + col] = (_Float16)acc[m][n][2];
        Cb[(size_t)(row0 + 3) * ldc + col] = (_Float16)acc[m][n][3];
      }
    }
    if (l16 == 0 && wcn == 0) {
      float2* sb = side + ((size_t)blockIdx.z * 2048 + bm0) * 8 + (bn0 >> 8);
#pragma unroll
      for (int m = 0; m < 8; ++m)
#pragma unroll
        for (int v = 0; v < 4; ++v) {
          int r = m * 32 + wr * 16 + lhi * 4 + v;
          sb[(size_t)r * 8] = make_float2(rm[m][v], rs[m][v]);
        }
    }
  }
}

// ---------------------------------------------------------------- global renorm
__global__ __launch_bounds__(256) void renorm_k(_Float16* __restrict__ P,
                                                const float2* __restrict__ side) {
  const int row = blockIdx.x;
  const int bz = blockIdx.y;
  const float2* sd = side + ((size_t)bz * 2048 + row) * 8;
  float mt[8], st[8];
#pragma unroll
  for (int t = 0; t < 8; ++t) { float2 v = sd[t]; mt[t] = v.x; st[t] = v.y; }
  float m = mt[0];
#pragma unroll
  for (int t = 1; t < 8; ++t) m = fmaxf(m, mt[t]);
  float S = 0.f;
#pragma unroll
  for (int t = 0; t < 8; ++t) S += st[t] * __expf(mt[t] - m);
  const float inv = 1.f / S;
  const int tid = threadIdx.x;
  const float sc = __expf(mt[tid >> 5] - m) * inv;
  _Float16* p = P + (((size_t)bz * 2048 + row) * 2048) + tid * 8;
  half8 v = *(half8*)p;
#pragma unroll
  for (int j = 0; j < 8; ++j) v[j] = (_Float16)((float)v[j] * sc);
  *(half8*)p = v;
}

// ---------------------------------------------------------------- launch
extern "C" void kernel_launch(void* const* d_in, const int* in_sizes, int n_in,
                              void* d_out, int out_size, void* d_ws, size_t ws_size,
                              hipStream_t stream) {
  const float* q = (const float*)d_in[0];
  const float* p = (const float*)d_in[1];
  const float* W = (const float*)d_in[2];
  const float* bias = (const float*)d_in[3];
  float* out = (float*)d_out;
  char* ws = (char*)d_ws;

  _Float16* qf    = (_Float16*)(ws);
  _Float16* pf    = (_Float16*)(ws + 67108864L);
  _Float16* qlin  = (_Float16*)(ws + 134217728L);
  _Float16* plin  = (_Float16*)(ws + 201326592L);
  _Float16* qlinT = (_Float16*)(ws + 268435456L);
  _Float16* Wf    = (_Float16*)(ws + 335544320L);
  _Float16* Pbuf  = (_Float16*)(ws);
  float2*   side  = (float2*)(ws + 67108864L);

  const long nQ = (long)NBATCH * LQN * HD;
  const size_t SH = 65536;

  cvt_f32_f16<<<2048, 256, 0, stream>>>(q, qf, nQ / 4);
  cvt_f32_f16<<<2048, 256, 0, stream>>>(p, pf, nQ / 4);
  cvt_f32_f16<<<64, 256, 0, stream>>>(W, Wf, (long)HD * HD / 4);

  gemm8p<1><<<dim3(HD / 256, 2 * NBATCH * LQN / 256, 1), 512, SH, stream>>>(
      qf, Wf, bias, qlin, (float2*)0, HD, HD, HD, HD, 0, 0, 0);

  transpose_k<<<dim3(LQN / 64, HD / 64, NBATCH), 256, 0, stream>>>(qlin, qlinT);

  for (int c = 0; c < 2; ++c) {
    int bz0 = c * 8;
    gemm8p<2><<<dim3(LQN / 256, LPN / 256, 8), 512, SH, stream>>>(
        plin + (size_t)bz0 * LPN * HD, qlin + (size_t)bz0 * LQN * HD,
        (const float*)0, Pbuf, side,
        /*K=*/HD, /*lda=*/HD, /*ldb=*/HD, /*ldc=*/LQN,
        (long)LPN * HD, (long)LQN * HD, (long)LPN * LQN);
    renorm_k<<<dim3(LPN, 8), 256, 0, stream>>>(Pbuf, side);
    gemm8p<0><<<dim3(HD / 256, LPN / 256, 8), 512, SH, stream>>>(
        Pbuf, qlinT + (size_t)bz0 * HD * LQN,
        (const float*)0, out + (size_t)bz0 * LPN * HD, (float2*)0,
        /*K=*/LQN, /*lda=*/LQN, /*ldb=*/LQN, /*ldc=*/HD,
        (long)LPN * LQN, (long)HD * LQN, (long)LPN * HD);
  }
}

// Round 11
// 590.409 us; speedup vs baseline: 1.3626x; 1.3626x over previous
//
#include <hip/hip_runtime.h>

// B=16, LQ=LP=2048, H=1024
//   q_lin = relu(q @ W^T + b); p_lin = relu(p @ W^T + b)
//   scores = p_lin @ q_lin^T ; att = softmax(scores); out = att @ q_lin
// Round-11: r7 8-phase core for scores/PV (best measured). NEW lin_gemm
// reads q/p as f32 directly and converts during reg-staging (T14 split),
// eliminating the 384MB cvt pass. r10's B-in-regs reverted (uncoalesced).

#define LQN 2048
#define LPN 2048
#define HD  1024
#define NBATCH 16

typedef _Float16 half8 __attribute__((ext_vector_type(8)));
typedef _Float16 half4_t __attribute__((ext_vector_type(4)));
typedef float f32x4 __attribute__((ext_vector_type(4)));

#define GLP(src, dst) __builtin_amdgcn_global_load_lds(                          \
    (const __attribute__((address_space(1))) void*)(src),                        \
    (__attribute__((address_space(3))) void*)(dst), 16, 0, 0)

// ---------------------------------------------------------------- convert f32->f16 (W only)
__global__ __launch_bounds__(256) void cvt_f32_f16(const float* __restrict__ in,
                                                   _Float16* __restrict__ out,
                                                   long n4) {
  long i0 = (long)blockIdx.x * blockDim.x + threadIdx.x;
  long stride = (long)gridDim.x * blockDim.x;
  for (long i = i0; i < n4; i += stride) {
    float4 v = ((const float4*)in)[i];
    half4_t h = {(_Float16)v.x, (_Float16)v.y, (_Float16)v.z, (_Float16)v.w};
    ((half4_t*)out)[i] = h;
  }
}

// ---------------------------------------------------------------- tiled transpose
__global__ __launch_bounds__(256) void transpose_k(const _Float16* __restrict__ in,
                                                   _Float16* __restrict__ out) {
  __shared__ _Float16 t[64][72];
  const int bz = blockIdx.z;
  const int q0 = blockIdx.x * 64;
  const int d0 = blockIdx.y * 64;
  const int tt = threadIdx.x;
  const int ql = tt & 63, dg = tt >> 6;
  const _Float16* src = in + ((size_t)bz * LQN + q0 + ql) * HD + d0 + dg * 16;
  half8 v0 = *(const half8*)(src);
  half8 v1 = *(const half8*)(src + 8);
  int g0 = (dg * 2) ^ (ql & 7);
  int g1 = (dg * 2 + 1) ^ (ql & 7);
  *(half8*)&t[ql][g0 * 8] = v0;
  *(half8*)&t[ql][g1 * 8] = v1;
  __syncthreads();
  const int dl = tt & 63, qg = tt >> 6;
  half8 o0, o1;
#pragma unroll
  for (int j = 0; j < 8; ++j) {
    int qq = qg * 16 + j;
    o0[j] = t[qq][(((dl >> 3) ^ (qq & 7)) << 3) + (dl & 7)];
  }
#pragma unroll
  for (int j = 0; j < 8; ++j) {
    int qq = qg * 16 + 8 + j;
    o1[j] = t[qq][(((dl >> 3) ^ (qq & 7)) << 3) + (dl & 7)];
  }
  _Float16* dst = out + ((size_t)bz * HD + d0 + dl) * LQN + q0 + qg * 16;
  *(half8*)dst = o0;
  *(half8*)(dst + 8) = o1;
}

// ---------------------------------------------------------------- fused f32-in linear GEMM
// C[65536][1024] = relu([q|p](f32) @ W^T + bias) in fp16. 256^2 tile, BK=64,
// A reg-staged f32->f16 (T14 split), B (W, fp16) GLP-staged. One barrier/tile.

#define LIN_LD(sg, tc) do {                                                       \
  st[0] = *(const float4*)(gA32 + (size_t)((sg)*64) * 1024 + (size_t)(tc)*64);    \
  st[1] = *(const float4*)(gA32 + (size_t)((sg)*64) * 1024 + (size_t)(tc)*64 + 4);\
  st[2] = *(const float4*)(gA32 + (size_t)((sg)*64+64) * 1024 + (size_t)(tc)*64); \
  st[3] = *(const float4*)(gA32 + (size_t)((sg)*64+64) * 1024 + (size_t)(tc)*64 + 4);\
} while (0)

#define LIN_WR(sg, buf) do {                                                      \
  half8 h0, h1;                                                                   \
  h0[0]=(_Float16)st[0].x; h0[1]=(_Float16)st[0].y;                               \
  h0[2]=(_Float16)st[0].z; h0[3]=(_Float16)st[0].w;                               \
  h0[4]=(_Float16)st[1].x; h0[5]=(_Float16)st[1].y;                               \
  h0[6]=(_Float16)st[1].z; h0[7]=(_Float16)st[1].w;                               \
  h1[0]=(_Float16)st[2].x; h1[1]=(_Float16)st[2].y;                               \
  h1[2]=(_Float16)st[2].z; h1[3]=(_Float16)st[2].w;                               \
  h1[4]=(_Float16)st[3].x; h1[5]=(_Float16)st[3].y;                               \
  h1[6]=(_Float16)st[3].z; h1[7]=(_Float16)st[3].w;                               \
  *(half8*)(smWr + (buf)*32768 + (sg)*8192 + tid*16) = h0;                        \
  *(half8*)(smWr + (buf)*32768 + ((sg)+1)*8192 + tid*16) = h1;                    \
} while (0)

#define LIN_STB(tc, buf) do {                                                     \
  GLP(gB + (size_t)(tc)*64,                      smWr + 65536 + (buf)*32768 + wid*1024);         \
  GLP(gB + (size_t)64*1024  + (size_t)(tc)*64,   smWr + 65536 + (buf)*32768 +  8192 + wid*1024); \
  GLP(gB + (size_t)128*1024 + (size_t)(tc)*64,   smWr + 65536 + (buf)*32768 + 16384 + wid*1024); \
  GLP(gB + (size_t)192*1024 + (size_t)(tc)*64,   smWr + 65536 + (buf)*32768 + 24576 + wid*1024); \
} while (0)

#define LIN_LDA(qm, buf)                                                          \
  _Pragma("unroll")                                                               \
  for (int mi = 0; mi < 4; ++mi) {                                                \
    aA[mi][0] = *(const half8*)(smA + (buf)*32768 + a0 + ((qm)*4+mi)*4096);       \
    aA[mi][1] = *(const half8*)(smA + (buf)*32768 + a1 + ((qm)*4+mi)*4096);       \
  }

#define LIN_LDB(buf)                                                              \
  _Pragma("unroll")                                                               \
  for (int nb = 0; nb < 4; ++nb) {                                                \
    bf[nb][0] = *(const half8*)(smB + (buf)*32768 + b0 + (nb)*8192);              \
    bf[nb][1] = *(const half8*)(smB + (buf)*32768 + b1 + (nb)*8192);              \
  }

#define LIN_MFMA(qm)                                                              \
  _Pragma("unroll")                                                               \
  for (int mi = 0; mi < 4; ++mi) {                                                \
    _Pragma("unroll")                                                             \
    for (int nb = 0; nb < 4; ++nb) {                                              \
      acc[(qm)*4+mi][nb] = __builtin_amdgcn_mfma_f32_16x16x32_f16(                \
          aA[mi][0], bf[nb][0], acc[(qm)*4+mi][nb], 0, 0, 0);                     \
      acc[(qm)*4+mi][nb] = __builtin_amdgcn_mfma_f32_16x16x32_f16(                \
          aA[mi][1], bf[nb][1], acc[(qm)*4+mi][nb], 0, 0, 0);                     \
    }                                                                             \
  }

__global__ __launch_bounds__(512, 2) void lin_gemm(
    const float* __restrict__ Aq, const float* __restrict__ Ap,
    const _Float16* __restrict__ Bw, const float* __restrict__ bias,
    _Float16* __restrict__ C) {
  extern __shared__ __align__(16) char smem[];
  char* smWr = smem;
  const char* smA = smem;            // A: 2 x 32KB
  const char* smB = smem + 65536;    // B: 2 x 32KB

  const int tid = threadIdx.x;
  const int lane = tid & 63, wid = tid >> 6;
  const int l16 = lane & 15, lhi = lane >> 4;
  const int wr = wid >> 2, wcn = wid & 3;

  const int nx = gridDim.x;
  const int d = blockIdx.y * nx + blockIdx.x;
  const int cpx = (nx * gridDim.y) >> 3;
  const int t_ = (d & 7) * cpx + (d >> 3);
  const int xsh = 31 - __builtin_clz(nx);
  const int bn0 = (t_ & (nx - 1)) << 8;
  const int bm0 = (t_ >> xsh) << 8;

  const int mask = (l16 & 7) << 4;
  const int a0 = (wr * 2048 + l16 * 128 + lhi * 16) ^ mask;
  const int a1 = a0 ^ 64;
  const int b0 = (wcn * 2048 + l16 * 128 + lhi * 16) ^ mask;
  const int b1 = b0 ^ 64;

  const int srow = tid >> 3;
  const int scol = (((tid & 7) ^ ((tid >> 3) & 7)) << 3);

  const float* gA32 = (bm0 < 32768 ? Aq + (size_t)(bm0 + srow) * 1024
                                   : Ap + (size_t)(bm0 - 32768 + srow) * 1024) + scol;
  const _Float16* gB = Bw + (size_t)(bn0 + srow) * 1024 + scol;

  f32x4 acc[8][4] = {};
  half8 aA[4][2], bf[4][2];
  float4 st[4];

  // prologue: tile 0 into buf0
  LIN_LD(0, 0);
  asm volatile("s_waitcnt vmcnt(0)" ::: "memory");
  LIN_WR(0, 0);
  LIN_LD(2, 0);
  LIN_STB(0, 0);
  __builtin_amdgcn_sched_barrier(0);
  asm volatile("s_waitcnt vmcnt(4)" ::: "memory");  // retires the 4 A-loads
  LIN_WR(2, 0);
  __syncthreads();                                   // drains ds_writes + GLPs

  for (int t = 0; t < 16; ++t) {
    const int cur = t & 1, nxt = cur ^ 1;
    const int tc = (t < 15) ? t + 1 : 15;
    // issue next-tile staging: A f32 segs 0,1 + B GLPs
    LIN_LD(0, tc);
    LIN_STB(tc, nxt);
    __builtin_amdgcn_sched_barrier(0);
    // compute half 0 of tile t
    LIN_LDB(cur)
    LIN_LDA(0, cur)
    __builtin_amdgcn_s_setprio(1);
    LIN_MFMA(0)
    __builtin_amdgcn_s_setprio(0);
    __builtin_amdgcn_sched_barrier(0);
    asm volatile("s_waitcnt vmcnt(4)" ::: "memory");  // retires 4 A-loads (oldest)
    LIN_WR(0, nxt);
    LIN_LD(2, tc);
    __builtin_amdgcn_sched_barrier(0);
    // compute half 1 of tile t
    LIN_LDA(1, cur)
    __builtin_amdgcn_s_setprio(1);
    LIN_MFMA(1)
    __builtin_amdgcn_s_setprio(0);
    __builtin_amdgcn_sched_barrier(0);
    asm volatile("s_waitcnt vmcnt(0)" ::: "memory");  // A segs 2,3 ready
    LIN_WR(2, nxt);
    __syncthreads();
  }

  // epilogue: bias + relu, fp16
#pragma unroll
  for (int n = 0; n < 4; ++n) {
    int col = bn0 + n * 64 + wcn * 16 + l16;
    float bv = bias[col];
#pragma unroll
    for (int m = 0; m < 8; ++m) {
      int row0 = bm0 + m * 32 + wr * 16 + lhi * 4;
      C[(size_t)(row0 + 0) * 1024 + col] = (_Float16)fmaxf(acc[m][n][0] + bv, 0.f);
      C[(size_t)(row0 + 1) * 1024 + col] = (_Float16)fmaxf(acc[m][n][1] + bv, 0.f);
      C[(size_t)(row0 + 2) * 1024 + col] = (_Float16)fmaxf(acc[m][n][2] + bv, 0.f);
      C[(size_t)(row0 + 3) * 1024 + col] = (_Float16)fmaxf(acc[m][n][3] + bv, 0.f);
    }
  }
}

// ---------------------------------------------------------------- 8-phase 256^2 GEMM (r7 core)
// EPI 0: f32 C (+z*sCz).  EPI 2: fp16 P_t = exp(s-m_t) + side (m_t, sum_t).

#define SYNC_PRE                                        \
  __builtin_amdgcn_s_barrier();                         \
  __builtin_amdgcn_s_setprio(1);

#define SYNC_POST                                       \
  __builtin_amdgcn_s_setprio(0);                        \
  __builtin_amdgcn_s_barrier();                         \
  __builtin_amdgcn_sched_barrier(0);

#define SYNC_POST_VM                                    \
  __builtin_amdgcn_s_setprio(0);                        \
  asm volatile("s_waitcnt vmcnt(4)" ::: "memory");      \
  __builtin_amdgcn_s_barrier();                         \
  __builtin_amdgcn_sched_barrier(0);

#define LOADA(qm, buf)                                                            \
  _Pragma("unroll")                                                               \
  for (int mi = 0; mi < 4; ++mi) {                                                \
    areg[mi][0] = *(const half8*)(smA + (buf)*32768 + a0 + ((qm)*4+mi)*4096);     \
    areg[mi][1] = *(const half8*)(smA + (buf)*32768 + a1 + ((qm)*4+mi)*4096);     \
  }

#define LOADB(qn, buf)                                                            \
  _Pragma("unroll")                                                               \
  for (int ni = 0; ni < 2; ++ni) {                                                \
    bregs[qn][ni][0] = *(const half8*)(smB + (buf)*32768 + b0 + ((qn)*2+ni)*8192);\
    bregs[qn][ni][1] = *(const half8*)(smB + (buf)*32768 + b1 + ((qn)*2+ni)*8192);\
  }

#define STAGEA(t, h, buf) do {                                                    \
  GLP(gA + (size_t)((h)*128)*lda + (size_t)(t)*64,                                \
      smW + (buf)*32768 + (h)*16384 + wid*1024);                                  \
  GLP(gA + (size_t)((h)*128+64)*lda + (size_t)(t)*64,                             \
      smW + (buf)*32768 + (h)*16384 + 8192 + wid*1024);                           \
} while (0)

#define STAGEB(t, h, buf) do {                                                    \
  GLP(gB + (size_t)((h)*128)*ldb + (size_t)(t)*64,                                \
      smW + 65536 + (buf)*32768 + (h)*16384 + wid*1024);                          \
  GLP(gB + (size_t)((h)*128+64)*ldb + (size_t)(t)*64,                             \
      smW + 65536 + (buf)*32768 + (h)*16384 + 8192 + wid*1024);                   \
} while (0)

#define DO_MFMA(qm, qn)                                                           \
  _Pragma("unroll")                                                               \
  for (int mi = 0; mi < 4; ++mi) {                                                \
    _Pragma("unroll")                                                             \
    for (int ni = 0; ni < 2; ++ni) {                                              \
      acc[(qm)*4+mi][(qn)*2+ni] = __builtin_amdgcn_mfma_f32_16x16x32_f16(         \
          areg[mi][0], bregs[qn][ni][0], acc[(qm)*4+mi][(qn)*2+ni], 0, 0, 0);     \
      acc[(qm)*4+mi][(qn)*2+ni] = __builtin_amdgcn_mfma_f32_16x16x32_f16(         \
          areg[mi][1], bregs[qn][ni][1], acc[(qm)*4+mi][(qn)*2+ni], 0, 0, 0);     \
    }                                                                             \
  }

template <int EPI>
__global__ __launch_bounds__(512, 2) void gemm8p(
    const _Float16* __restrict__ A, const _Float16* __restrict__ B,
    const float* __restrict__ bias, void* __restrict__ Cv,
    float2* __restrict__ side, int K, int lda, int ldb, int ldc,
    long sAz, long sBz, long sCz) {
  extern __shared__ __align__(16) char smem[];
  const char* smA = smem;
  const char* smB = smem + 65536;
  char* smW = smem;

  const int tid = threadIdx.x;
  const int lane = tid & 63, wid = tid >> 6;
  const int l16 = lane & 15, lhi = lane >> 4;
  const int wr = wid >> 2, wcn = wid & 3;

  const int nx = gridDim.x;
  const int d = blockIdx.y * nx + blockIdx.x;
  const int cpx = (nx * gridDim.y) >> 3;
  const int t_ = (d & 7) * cpx + (d >> 3);
  const int xsh = 31 - __builtin_clz(nx);
  const int bn0 = (t_ & (nx - 1)) << 8;
  const int bm0 = (t_ >> xsh) << 8;

  const int mask = (l16 & 7) << 4;
  const int a0 = (wr * 2048 + l16 * 128 + lhi * 16) ^ mask;
  const int a1 = a0 ^ 64;
  const int b0 = (wcn * 2048 + l16 * 128 + lhi * 16) ^ mask;
  const int b1 = b0 ^ 64;

  const int srow = tid >> 3;
  const int scol = (((tid & 7) ^ ((tid >> 3) & 7)) << 3);

  const _Float16* gA = A + (size_t)blockIdx.z * sAz + (size_t)(bm0 + srow) * lda + scol;
  const _Float16* gB = B + (size_t)blockIdx.z * sBz + (size_t)(bn0 + srow) * ldb + scol;

  const int NT = K >> 6, NI = K >> 7;

  f32x4 acc[8][4] = {};
  half8 areg[4][2], bregs[2][2][2];

  STAGEA(0, 0, 0); STAGEB(0, 0, 0);
  STAGEA(0, 1, 0); STAGEB(0, 1, 0);
  STAGEA(1, 0, 1); STAGEB(1, 0, 1);
  __builtin_amdgcn_sched_barrier(0);
  asm volatile("s_waitcnt vmcnt(4)" ::: "memory");
  __builtin_amdgcn_s_barrier();
  __builtin_amdgcn_sched_barrier(0);

  for (int i = 0; i < NI; ++i) {
    const int t1 = 2 * i + 1;
    int t2 = 2 * i + 2; if (t2 > NT - 1) t2 = NT - 1;
    int t3 = 2 * i + 3; if (t3 > NT - 1) t3 = NT - 1;
    STAGEA(t1, 1, 1); LOADA(0, 0) LOADB(0, 0)
    SYNC_PRE DO_MFMA(0, 0) SYNC_POST
    STAGEB(t1, 1, 1); LOADB(1, 0)
    SYNC_PRE DO_MFMA(0, 1) SYNC_POST
    STAGEA(t2, 0, 0); LOADA(1, 0)
    SYNC_PRE DO_MFMA(1, 0) SYNC_POST
    STAGEB(t2, 0, 0);
    SYNC_PRE DO_MFMA(1, 1) SYNC_POST_VM
    STAGEA(t2, 1, 0); LOADA(0, 1) LOADB(0, 1)
    SYNC_PRE DO_MFMA(0, 0) SYNC_POST
    STAGEB(t2, 1, 0); LOADB(1, 1)
    SYNC_PRE DO_MFMA(0, 1) SYNC_POST
    STAGEA(t3, 0, 1); LOADA(1, 1)
    SYNC_PRE DO_MFMA(1, 0) SYNC_POST
    STAGEB(t3, 0, 1);
    SYNC_PRE DO_MFMA(1, 1) SYNC_POST_VM
  }

  if constexpr (EPI == 0) {
    float* Cb = (float*)Cv + (size_t)blockIdx.z * sCz;
#pragma unroll
    for (int m = 0; m < 8; ++m) {
      int row0 = bm0 + m * 32 + wr * 16 + lhi * 4;
#pragma unroll
      for (int n = 0; n < 4; ++n) {
        int col = bn0 + n * 64 + wcn * 16 + l16;
#pragma unroll
        for (int v = 0; v < 4; ++v)
          Cb[(size_t)(row0 + v) * ldc + col] = acc[m][n][v];
      }
    }
  } else {
    // EPI == 2: partial softmax over this block's 256 cols.
    float* redm = (float*)smW;            // [256][4]
    float* reds = (float*)(smW + 4096);   // [256][4]
    float tm[8][4];
#pragma unroll
    for (int m = 0; m < 8; ++m)
#pragma unroll
      for (int v = 0; v < 4; ++v)
        tm[m][v] = fmaxf(fmaxf(acc[m][0][v], acc[m][1][v]),
                         fmaxf(acc[m][2][v], acc[m][3][v]));
#pragma unroll
    for (int o = 1; o < 16; o <<= 1)
#pragma unroll
      for (int m = 0; m < 8; ++m)
#pragma unroll
        for (int v = 0; v < 4; ++v)
          tm[m][v] = fmaxf(tm[m][v], __shfl_xor(tm[m][v], o));
    __syncthreads();
    if (l16 == 0) {
#pragma unroll
      for (int m = 0; m < 8; ++m)
#pragma unroll
        for (int v = 0; v < 4; ++v)
          redm[(m * 32 + wr * 16 + lhi * 4 + v) * 4 + wcn] = tm[m][v];
    }
    __syncthreads();
    float rm[8][4], rs[8][4];
#pragma unroll
    for (int m = 0; m < 8; ++m)
#pragma unroll
      for (int v = 0; v < 4; ++v) {
        float4 q4 = ((const float4*)redm)[m * 32 + wr * 16 + lhi * 4 + v];
        rm[m][v] = fmaxf(fmaxf(q4.x, q4.y), fmaxf(q4.z, q4.w));
      }
#pragma unroll
    for (int m = 0; m < 8; ++m)
#pragma unroll
      for (int v = 0; v < 4; ++v) {
        float s = 0.f;
#pragma unroll
        for (int n = 0; n < 4; ++n) {
          float e = __expf(acc[m][n][v] - rm[m][v]);
          acc[m][n][v] = e;
          s += e;
        }
        tm[m][v] = s;
      }
#pragma unroll
    for (int o = 1; o < 16; o <<= 1)
#pragma unroll
      for (int m = 0; m < 8; ++m)
#pragma unroll
        for (int v = 0; v < 4; ++v)
          tm[m][v] += __shfl_xor(tm[m][v], o);
    __syncthreads();
    if (l16 == 0) {
#pragma unroll
      for (int m = 0; m < 8; ++m)
#pragma unroll
        for (int v = 0; v < 4; ++v)
          reds[(m * 32 + wr * 16 + lhi * 4 + v) * 4 + wcn] = tm[m][v];
    }
    __syncthreads();
#pragma unroll
    for (int m = 0; m < 8; ++m)
#pragma unroll
      for (int v = 0; v < 4; ++v) {
        float4 q4 = ((const float4*)reds)[m * 32 + wr * 16 + lhi * 4 + v];
        rs[m][v] = (q4.x + q4.y) + (q4.z + q4.w);
      }
    _Float16* Cb = (_Float16*)Cv + (size_t)blockIdx.z * sCz;
#pragma unroll
    for (int n = 0; n < 4; ++n) {
      int col = bn0 + n * 64 + wcn * 16 + l16;
#pragma unroll
      for (int m = 0; m < 8; ++m) {
        int row0 = bm0 + m * 32 + wr * 16 + lhi * 4;
        Cb[(size_t)(row0 + 0) * ldc + col] = (_Float16)acc[m][n][0];
        Cb[(size_t)(row0 + 1) * ldc + col] = (_Float16)acc[m][n][1];
        Cb[(size_t)(row0 + 2) * ldc + col] = (_Float16)acc[m][n][2];
        Cb[(size_t)(row0 + 3) * ldc + col] = (_Float16)acc[m][n][3];
      }
    }
    if (l16 == 0 && wcn == 0) {
      float2* sb = side + ((size_t)blockIdx.z * 2048 + bm0) * 8 + (bn0 >> 8);
#pragma unroll
      for (int m = 0; m < 8; ++m)
#pragma unroll
        for (int v = 0; v < 4; ++v) {
          int r = m * 32 + wr * 16 + lhi * 4 + v;
          sb[(size_t)r * 8] = make_float2(rm[m][v], rs[m][v]);
        }
    }
  }
}

// ---------------------------------------------------------------- global renorm
__global__ __launch_bounds__(256) void renorm_k(_Float16* __restrict__ P,
                                                const float2* __restrict__ side) {
  const int row = blockIdx.x;
  const int bz = blockIdx.y;
  const float2* sd = side + ((size_t)bz * 2048 + row) * 8;
  float mt[8], st[8];
#pragma unroll
  for (int t = 0; t < 8; ++t) { float2 v = sd[t]; mt[t] = v.x; st[t] = v.y; }
  float m = mt[0];
#pragma unroll
  for (int t = 1; t < 8; ++t) m = fmaxf(m, mt[t]);
  float S = 0.f;
#pragma unroll
  for (int t = 0; t < 8; ++t) S += st[t] * __expf(mt[t] - m);
  const float inv = 1.f / S;
  const int tid = threadIdx.x;
  const float sc = __expf(mt[tid >> 5] - m) * inv;
  _Float16* p = P + (((size_t)bz * 2048 + row) * 2048) + tid * 8;
  half8 v = *(half8*)p;
#pragma unroll
  for (int j = 0; j < 8; ++j) v[j] = (_Float16)((float)v[j] * sc);
  *(half8*)p = v;
}

// ---------------------------------------------------------------- launch
extern "C" void kernel_launch(void* const* d_in, const int* in_sizes, int n_in,
                              void* d_out, int out_size, void* d_ws, size_t ws_size,
                              hipStream_t stream) {
  const float* q = (const float*)d_in[0];
  const float* p = (const float*)d_in[1];
  const float* W = (const float*)d_in[2];
  const float* bias = (const float*)d_in[3];
  float* out = (float*)d_out;
  char* ws = (char*)d_ws;

  _Float16* qlin  = (_Float16*)(ws + 134217728L);
  _Float16* plin  = (_Float16*)(ws + 201326592L);   // contiguous with qlin
  _Float16* qlinT = (_Float16*)(ws + 268435456L);
  _Float16* Wf    = (_Float16*)(ws + 335544320L);
  _Float16* Pbuf  = (_Float16*)(ws);
  float2*   side  = (float2*)(ws + 67108864L);

  const size_t SH = 131072;

  cvt_f32_f16<<<64, 256, 0, stream>>>(W, Wf, (long)HD * HD / 4);

  // fused f32-in shared linear + relu over q|p (M=65536)
  lin_gemm<<<dim3(HD / 256, 2 * NBATCH * LQN / 256), 512, SH, stream>>>(
      q, p, Wf, bias, qlin);

  transpose_k<<<dim3(LQN / 64, HD / 64, NBATCH), 256, 0, stream>>>(qlin, qlinT);

  for (int c = 0; c < 2; ++c) {
    int bz0 = c * 8;
    gemm8p<2><<<dim3(LQN / 256, LPN / 256, 8), 512, SH, stream>>>(
        plin + (size_t)bz0 * LPN * HD, qlin + (size_t)bz0 * LQN * HD,
        (const float*)0, Pbuf, side,
        /*K=*/HD, /*lda=*/HD, /*ldb=*/HD, /*ldc=*/LQN,
        (long)LPN * HD, (long)LQN * HD, (long)LPN * LQN);
    renorm_k<<<dim3(LPN, 8), 256, 0, stream>>>(Pbuf, side);
    gemm8p<0><<<dim3(HD / 256, LPN / 256, 8), 512, SH, stream>>>(
        Pbuf, qlinT + (size_t)bz0 * HD * LQN,
        (const float*)0, out + (size_t)bz0 * LPN * HD, (float2*)0,
        /*K=*/LQN, /*lda=*/LQN, /*ldb=*/LQN, /*ldc=*/HD,
        (long)LPN * LQN, (long)HD * LQN, (long)LPN * HD);
  }
}

// Round 12
// 585.639 us; speedup vs baseline: 1.3737x; 1.0081x over previous
//
#include <hip/hip_runtime.h>

// B=16, LQ=LP=2048, H=1024
//   q_lin = relu(q @ W^T + b); p_lin = relu(p @ W^T + b)
//   scores = p_lin @ q_lin^T ; att = softmax(scores); out = att @ q_lin
// Round-12: r7 8-phase GEMM core (best of 6 schedule variants). Launch-level
// restructure: single-chunk attention (z=16, one scores/renorm/PV dispatch),
// merged q+p convert. r11's f32-fused linear reverted (257us vs 157+44).

#define LQN 2048
#define LPN 2048
#define HD  1024
#define NBATCH 16

typedef _Float16 half8 __attribute__((ext_vector_type(8)));
typedef _Float16 half4_t __attribute__((ext_vector_type(4)));
typedef float f32x4 __attribute__((ext_vector_type(4)));

#define GLP(src, dst) __builtin_amdgcn_global_load_lds(                          \
    (const __attribute__((address_space(1))) void*)(src),                        \
    (__attribute__((address_space(3))) void*)(dst), 16, 0, 0)

// ---------------------------------------------------------------- converts
__global__ __launch_bounds__(256) void cvt_f32_f16(const float* __restrict__ in,
                                                   _Float16* __restrict__ out,
                                                   long n4) {
  long i0 = (long)blockIdx.x * blockDim.x + threadIdx.x;
  long stride = (long)gridDim.x * blockDim.x;
  for (long i = i0; i < n4; i += stride) {
    float4 v = ((const float4*)in)[i];
    half4_t h = {(_Float16)v.x, (_Float16)v.y, (_Float16)v.z, (_Float16)v.w};
    ((half4_t*)out)[i] = h;
  }
}

// merged q+p convert: [0,n4each) -> qf, [n4each,2*n4each) -> pf
__global__ __launch_bounds__(256) void cvt2_f32_f16(const float* __restrict__ q,
                                                    const float* __restrict__ p,
                                                    _Float16* __restrict__ qf,
                                                    _Float16* __restrict__ pf,
                                                    long n4each) {
  long i0 = (long)blockIdx.x * blockDim.x + threadIdx.x;
  long stride = (long)gridDim.x * blockDim.x;
  for (long i = i0; i < 2 * n4each; i += stride) {
    const float* src = (i < n4each) ? q : p;
    _Float16* dst = (i < n4each) ? qf : pf;
    long j = (i < n4each) ? i : i - n4each;
    float4 v = ((const float4*)src)[j];
    half4_t h = {(_Float16)v.x, (_Float16)v.y, (_Float16)v.z, (_Float16)v.w};
    ((half4_t*)dst)[j] = h;
  }
}

// ---------------------------------------------------------------- tiled transpose
__global__ __launch_bounds__(256) void transpose_k(const _Float16* __restrict__ in,
                                                   _Float16* __restrict__ out) {
  __shared__ _Float16 t[64][72];
  const int bz = blockIdx.z;
  const int q0 = blockIdx.x * 64;
  const int d0 = blockIdx.y * 64;
  const int tt = threadIdx.x;
  const int ql = tt & 63, dg = tt >> 6;
  const _Float16* src = in + ((size_t)bz * LQN + q0 + ql) * HD + d0 + dg * 16;
  half8 v0 = *(const half8*)(src);
  half8 v1 = *(const half8*)(src + 8);
  int g0 = (dg * 2) ^ (ql & 7);
  int g1 = (dg * 2 + 1) ^ (ql & 7);
  *(half8*)&t[ql][g0 * 8] = v0;
  *(half8*)&t[ql][g1 * 8] = v1;
  __syncthreads();
  const int dl = tt & 63, qg = tt >> 6;
  half8 o0, o1;
#pragma unroll
  for (int j = 0; j < 8; ++j) {
    int qq = qg * 16 + j;
    o0[j] = t[qq][(((dl >> 3) ^ (qq & 7)) << 3) + (dl & 7)];
  }
#pragma unroll
  for (int j = 0; j < 8; ++j) {
    int qq = qg * 16 + 8 + j;
    o1[j] = t[qq][(((dl >> 3) ^ (qq & 7)) << 3) + (dl & 7)];
  }
  _Float16* dst = out + ((size_t)bz * HD + d0 + dl) * LQN + q0 + qg * 16;
  *(half8*)dst = o0;
  *(half8*)(dst + 8) = o1;
}

// ---------------------------------------------------------------- 8-phase 256^2 GEMM (r7 core)
// EPI 0: f32 C (+z*sCz).  EPI 1: fp16 C = relu(acc+bias).
// EPI 2: fp16 P_t = exp(s - m_t) per 256-col tile + side (m_t, sum_t).

#define SYNC_PRE                                        \
  __builtin_amdgcn_s_barrier();                         \
  __builtin_amdgcn_s_setprio(1);

#define SYNC_POST                                       \
  __builtin_amdgcn_s_setprio(0);                        \
  __builtin_amdgcn_s_barrier();                         \
  __builtin_amdgcn_sched_barrier(0);

#define SYNC_POST_VM                                    \
  __builtin_amdgcn_s_setprio(0);                        \
  asm volatile("s_waitcnt vmcnt(4)" ::: "memory");      \
  __builtin_amdgcn_s_barrier();                         \
  __builtin_amdgcn_sched_barrier(0);

#define LOADA(qm, buf)                                                            \
  _Pragma("unroll")                                                               \
  for (int mi = 0; mi < 4; ++mi) {                                                \
    areg[mi][0] = *(const half8*)(smA + (buf)*32768 + a0 + ((qm)*4+mi)*4096);     \
    areg[mi][1] = *(const half8*)(smA + (buf)*32768 + a1 + ((qm)*4+mi)*4096);     \
  }

#define LOADB(qn, buf)                                                            \
  _Pragma("unroll")                                                               \
  for (int ni = 0; ni < 2; ++ni) {                                                \
    bregs[qn][ni][0] = *(const half8*)(smB + (buf)*32768 + b0 + ((qn)*2+ni)*8192);\
    bregs[qn][ni][1] = *(const half8*)(smB + (buf)*32768 + b1 + ((qn)*2+ni)*8192);\
  }

#define STAGEA(t, h, buf) do {                                                    \
  GLP(gA + (size_t)((h)*128)*lda + (size_t)(t)*64,                                \
      smW + (buf)*32768 + (h)*16384 + wid*1024);                                  \
  GLP(gA + (size_t)((h)*128+64)*lda + (size_t)(t)*64,                             \
      smW + (buf)*32768 + (h)*16384 + 8192 + wid*1024);                           \
} while (0)

#define STAGEB(t, h, buf) do {                                                    \
  GLP(gB + (size_t)((h)*128)*ldb + (size_t)(t)*64,                                \
      smW + 65536 + (buf)*32768 + (h)*16384 + wid*1024);                          \
  GLP(gB + (size_t)((h)*128+64)*ldb + (size_t)(t)*64,                             \
      smW + 65536 + (buf)*32768 + (h)*16384 + 8192 + wid*1024);                   \
} while (0)

#define DO_MFMA(qm, qn)                                                           \
  _Pragma("unroll")                                                               \
  for (int mi = 0; mi < 4; ++mi) {                                                \
    _Pragma("unroll")                                                             \
    for (int ni = 0; ni < 2; ++ni) {                                              \
      acc[(qm)*4+mi][(qn)*2+ni] = __builtin_amdgcn_mfma_f32_16x16x32_f16(         \
          areg[mi][0], bregs[qn][ni][0], acc[(qm)*4+mi][(qn)*2+ni], 0, 0, 0);     \
      acc[(qm)*4+mi][(qn)*2+ni] = __builtin_amdgcn_mfma_f32_16x16x32_f16(         \
          areg[mi][1], bregs[qn][ni][1], acc[(qm)*4+mi][(qn)*2+ni], 0, 0, 0);     \
    }                                                                             \
  }

template <int EPI>
__global__ __launch_bounds__(512, 2) void gemm8p(
    const _Float16* __restrict__ A, const _Float16* __restrict__ B,
    const float* __restrict__ bias, void* __restrict__ Cv,
    float2* __restrict__ side, int K, int lda, int ldb, int ldc,
    long sAz, long sBz, long sCz) {
  extern __shared__ __align__(16) char smem[];
  const char* smA = smem;
  const char* smB = smem + 65536;
  char* smW = smem;

  const int tid = threadIdx.x;
  const int lane = tid & 63, wid = tid >> 6;
  const int l16 = lane & 15, lhi = lane >> 4;
  const int wr = wid >> 2, wcn = wid & 3;

  // N-fast + XCD-chunked mapping
  const int nx = gridDim.x;
  const int d = blockIdx.y * nx + blockIdx.x;
  const int cpx = (nx * gridDim.y) >> 3;
  const int t_ = (d & 7) * cpx + (d >> 3);
  const int xsh = 31 - __builtin_clz(nx);
  const int bn0 = (t_ & (nx - 1)) << 8;
  const int bm0 = (t_ >> xsh) << 8;

  // swizzle: flip 16B-slot bits 4-6 by row bits 0-2
  const int mask = (l16 & 7) << 4;
  const int a0 = (wr * 2048 + l16 * 128 + lhi * 16) ^ mask;
  const int a1 = a0 ^ 64;
  const int b0 = (wcn * 2048 + l16 * 128 + lhi * 16) ^ mask;
  const int b1 = b0 ^ 64;

  const int srow = tid >> 3;
  const int scol = (((tid & 7) ^ ((tid >> 3) & 7)) << 3);

  const _Float16* gA = A + (size_t)blockIdx.z * sAz + (size_t)(bm0 + srow) * lda + scol;
  const _Float16* gB = B + (size_t)blockIdx.z * sBz + (size_t)(bn0 + srow) * ldb + scol;

  const int NT = K >> 6, NI = K >> 7;

  f32x4 acc[8][4] = {};
  half8 areg[4][2], bregs[2][2][2];

  STAGEA(0, 0, 0); STAGEB(0, 0, 0);
  STAGEA(0, 1, 0); STAGEB(0, 1, 0);
  STAGEA(1, 0, 1); STAGEB(1, 0, 1);
  __builtin_amdgcn_sched_barrier(0);
  asm volatile("s_waitcnt vmcnt(4)" ::: "memory");
  __builtin_amdgcn_s_barrier();
  __builtin_amdgcn_sched_barrier(0);

  for (int i = 0; i < NI; ++i) {
    const int t1 = 2 * i + 1;
    int t2 = 2 * i + 2; if (t2 > NT - 1) t2 = NT - 1;
    int t3 = 2 * i + 3; if (t3 > NT - 1) t3 = NT - 1;
    STAGEA(t1, 1, 1); LOADA(0, 0) LOADB(0, 0)
    SYNC_PRE DO_MFMA(0, 0) SYNC_POST
    STAGEB(t1, 1, 1); LOADB(1, 0)
    SYNC_PRE DO_MFMA(0, 1) SYNC_POST
    STAGEA(t2, 0, 0); LOADA(1, 0)
    SYNC_PRE DO_MFMA(1, 0) SYNC_POST
    STAGEB(t2, 0, 0);
    SYNC_PRE DO_MFMA(1, 1) SYNC_POST_VM
    STAGEA(t2, 1, 0); LOADA(0, 1) LOADB(0, 1)
    SYNC_PRE DO_MFMA(0, 0) SYNC_POST
    STAGEB(t2, 1, 0); LOADB(1, 1)
    SYNC_PRE DO_MFMA(0, 1) SYNC_POST
    STAGEA(t3, 0, 1); LOADA(1, 1)
    SYNC_PRE DO_MFMA(1, 0) SYNC_POST
    STAGEB(t3, 0, 1);
    SYNC_PRE DO_MFMA(1, 1) SYNC_POST_VM
  }

  if constexpr (EPI == 0) {
    float* Cb = (float*)Cv + (size_t)blockIdx.z * sCz;
#pragma unroll
    for (int m = 0; m < 8; ++m) {
      int row0 = bm0 + m * 32 + wr * 16 + lhi * 4;
#pragma unroll
      for (int n = 0; n < 4; ++n) {
        int col = bn0 + n * 64 + wcn * 16 + l16;
#pragma unroll
        for (int v = 0; v < 4; ++v)
          Cb[(size_t)(row0 + v) * ldc + col] = acc[m][n][v];
      }
    }
  } else if constexpr (EPI == 1) {
    _Float16* Cb = (_Float16*)Cv;
#pragma unroll
    for (int n = 0; n < 4; ++n) {
      int col = bn0 + n * 64 + wcn * 16 + l16;
      float bv = bias[col];
#pragma unroll
      for (int m = 0; m < 8; ++m) {
        int row0 = bm0 + m * 32 + wr * 16 + lhi * 4;
        Cb[(size_t)(row0 + 0) * ldc + col] = (_Float16)fmaxf(acc[m][n][0] + bv, 0.f);
        Cb[(size_t)(row0 + 1) * ldc + col] = (_Float16)fmaxf(acc[m][n][1] + bv, 0.f);
        Cb[(size_t)(row0 + 2) * ldc + col] = (_Float16)fmaxf(acc[m][n][2] + bv, 0.f);
        Cb[(size_t)(row0 + 3) * ldc + col] = (_Float16)fmaxf(acc[m][n][3] + bv, 0.f);
      }
    }
  } else {
    // EPI == 2: partial softmax over this block's 256 cols.
    float* redm = (float*)smW;            // [256][4]
    float* reds = (float*)(smW + 4096);   // [256][4]
    float tm[8][4];
#pragma unroll
    for (int m = 0; m < 8; ++m)
#pragma unroll
      for (int v = 0; v < 4; ++v)
        tm[m][v] = fmaxf(fmaxf(acc[m][0][v], acc[m][1][v]),
                         fmaxf(acc[m][2][v], acc[m][3][v]));
#pragma unroll
    for (int o = 1; o < 16; o <<= 1)
#pragma unroll
      for (int m = 0; m < 8; ++m)
#pragma unroll
        for (int v = 0; v < 4; ++v)
          tm[m][v] = fmaxf(tm[m][v], __shfl_xor(tm[m][v], o));
    __syncthreads();
    if (l16 == 0) {
#pragma unroll
      for (int m = 0; m < 8; ++m)
#pragma unroll
        for (int v = 0; v < 4; ++v)
          redm[(m * 32 + wr * 16 + lhi * 4 + v) * 4 + wcn] = tm[m][v];
    }
    __syncthreads();
    float rm[8][4], rs[8][4];
#pragma unroll
    for (int m = 0; m < 8; ++m)
#pragma unroll
      for (int v = 0; v < 4; ++v) {
        float4 q4 = ((const float4*)redm)[m * 32 + wr * 16 + lhi * 4 + v];
        rm[m][v] = fmaxf(fmaxf(q4.x, q4.y), fmaxf(q4.z, q4.w));
      }
#pragma unroll
    for (int m = 0; m < 8; ++m)
#pragma unroll
      for (int v = 0; v < 4; ++v) {
        float s = 0.f;
#pragma unroll
        for (int n = 0; n < 4; ++n) {
          float e = __expf(acc[m][n][v] - rm[m][v]);
          acc[m][n][v] = e;
          s += e;
        }
        tm[m][v] = s;
      }
#pragma unroll
    for (int o = 1; o < 16; o <<= 1)
#pragma unroll
      for (int m = 0; m < 8; ++m)
#pragma unroll
        for (int v = 0; v < 4; ++v)
          tm[m][v] += __shfl_xor(tm[m][v], o);
    __syncthreads();
    if (l16 == 0) {
#pragma unroll
      for (int m = 0; m < 8; ++m)
#pragma unroll
        for (int v = 0; v < 4; ++v)
          reds[(m * 32 + wr * 16 + lhi * 4 + v) * 4 + wcn] = tm[m][v];
    }
    __syncthreads();
#pragma unroll
    for (int m = 0; m < 8; ++m)
#pragma unroll
      for (int v = 0; v < 4; ++v) {
        float4 q4 = ((const float4*)reds)[m * 32 + wr * 16 + lhi * 4 + v];
        rs[m][v] = (q4.x + q4.y) + (q4.z + q4.w);
      }
    _Float16* Cb = (_Float16*)Cv + (size_t)blockIdx.z * sCz;
#pragma unroll
    for (int n = 0; n < 4; ++n) {
      int col = bn0 + n * 64 + wcn * 16 + l16;
#pragma unroll
      for (int m = 0; m < 8; ++m) {
        int row0 = bm0 + m * 32 + wr * 16 + lhi * 4;
        Cb[(size_t)(row0 + 0) * ldc + col] = (_Float16)acc[m][n][0];
        Cb[(size_t)(row0 + 1) * ldc + col] = (_Float16)acc[m][n][1];
        Cb[(size_t)(row0 + 2) * ldc + col] = (_Float16)acc[m][n][2];
        Cb[(size_t)(row0 + 3) * ldc + col] = (_Float16)acc[m][n][3];
      }
    }
    if (l16 == 0 && wcn == 0) {
      float2* sb = side + ((size_t)blockIdx.z * 2048 + bm0) * 8 + (bn0 >> 8);
#pragma unroll
      for (int m = 0; m < 8; ++m)
#pragma unroll
        for (int v = 0; v < 4; ++v) {
          int r = m * 32 + wr * 16 + lhi * 4 + v;
          sb[(size_t)r * 8] = make_float2(rm[m][v], rs[m][v]);
        }
    }
  }
}

// ---------------------------------------------------------------- global renorm
__global__ __launch_bounds__(256) void renorm_k(_Float16* __restrict__ P,
                                                const float2* __restrict__ side) {
  const int row = blockIdx.x;
  const int bz = blockIdx.y;
  const float2* sd = side + ((size_t)bz * 2048 + row) * 8;
  float mt[8], st[8];
#pragma unroll
  for (int t = 0; t < 8; ++t) { float2 v = sd[t]; mt[t] = v.x; st[t] = v.y; }
  float m = mt[0];
#pragma unroll
  for (int t = 1; t < 8; ++t) m = fmaxf(m, mt[t]);
  float S = 0.f;
#pragma unroll
  for (int t = 0; t < 8; ++t) S += st[t] * __expf(mt[t] - m);
  const float inv = 1.f / S;
  const int tid = threadIdx.x;
  const float sc = __expf(mt[tid >> 5] - m) * inv;
  _Float16* p = P + (((size_t)bz * 2048 + row) * 2048) + tid * 8;
  half8 v = *(half8*)p;
#pragma unroll
  for (int j = 0; j < 8; ++j) v[j] = (_Float16)((float)v[j] * sc);
  *(half8*)p = v;
}

// ---------------------------------------------------------------- launch
extern "C" void kernel_launch(void* const* d_in, const int* in_sizes, int n_in,
                              void* d_out, int out_size, void* d_ws, size_t ws_size,
                              hipStream_t stream) {
  const float* q = (const float*)d_in[0];
  const float* p = (const float*)d_in[1];
  const float* W = (const float*)d_in[2];
  const float* bias = (const float*)d_in[3];
  float* out = (float*)d_out;
  char* ws = (char*)d_ws;

  // ws layout (bytes): qf[0,64M) pf[64M,128M) | qlin[128M,192M) plin[192M,256M)
  // qlinT[256M,320M) Wf[320M,322M) side[322M,324M). Pbuf reuses [0,128M).
  _Float16* qf    = (_Float16*)(ws);
  _Float16* pf    = (_Float16*)(ws + 67108864L);
  _Float16* qlin  = (_Float16*)(ws + 134217728L);
  _Float16* plin  = (_Float16*)(ws + 201326592L);
  _Float16* qlinT = (_Float16*)(ws + 268435456L);
  _Float16* Wf    = (_Float16*)(ws + 335544320L);
  float2*   side  = (float2*)(ws + 337641472L);
  _Float16* Pbuf  = (_Float16*)(ws);

  const long nQ = (long)NBATCH * LQN * HD;
  const size_t SH = 131072;

  cvt2_f32_f16<<<4096, 256, 0, stream>>>(q, p, qf, pf, nQ / 4);
  cvt_f32_f16<<<64, 256, 0, stream>>>(W, Wf, (long)HD * HD / 4);

  // fused shared linear + relu over q|p (M=65536); grid (N=4, M=512)
  gemm8p<1><<<dim3(HD / 256, 2 * NBATCH * LQN / 256, 1), 512, SH, stream>>>(
      qf, Wf, bias, qlin, (float2*)0, HD, HD, HD, HD, 0, 0, 0);

  transpose_k<<<dim3(LQN / 64, HD / 64, NBATCH), 256, 0, stream>>>(qlin, qlinT);

  // scores + partial softmax, ALL 16 batches: grid (8, 8, 16)
  gemm8p<2><<<dim3(LQN / 256, LPN / 256, NBATCH), 512, SH, stream>>>(
      plin, qlin, (const float*)0, Pbuf, side,
      /*K=*/HD, /*lda=*/HD, /*ldb=*/HD, /*ldc=*/LQN,
      (long)LPN * HD, (long)LQN * HD, (long)LPN * LQN);
  renorm_k<<<dim3(LPN, NBATCH), 256, 0, stream>>>(Pbuf, side);
  // PV: out = P @ qlinT^T, ALL batches: grid (4, 8, 16)
  gemm8p<0><<<dim3(HD / 256, LPN / 256, NBATCH), 512, SH, stream>>>(
      Pbuf, qlinT, (const float*)0, out, (float2*)0,
      /*K=*/LQN, /*lda=*/LQN, /*ldb=*/LQN, /*ldc=*/HD,
      (long)LPN * LQN, (long)HD * LQN, (long)LPN * HD);
}